// Round 8
// baseline (61.841 us; speedup 1.0000x reference)
//
#include <hip/hip_runtime.h>
#include <math.h>

#define HIDDEN 2048
#define NEXP   64
#define KSTEPS (HIDDEN/32)    // 64 MFMA k-steps
#define NT     4              // four 16-expert N-tiles
#define CHUNK  4              // k-steps per LDS ws chunk
#define NCH    (KSTEPS/CHUNK) // 16
#define CH_HALVES (CHUNK*4096)  // 16384 halves = 32 KB per chunk
#define WS_HALVES (KSTEPS*NT*2*64*8)   // 262144 halves = 512 KB

typedef _Float16 f16x8 __attribute__((ext_vector_type(8)));
typedef float    f32x4 __attribute__((ext_vector_type(4)));
typedef __attribute__((address_space(3))) unsigned int       lds_u32;
typedef __attribute__((address_space(1))) const unsigned int gbl_u32;

// ---------------- prep: W -> split-f16 MFMA B-fragments in ws ----------------
// ws halves layout: ks*4096 + nt*1024 + split*512 + lane*8
// B-frag mapping (16x16x32): col(expert) = lane&15, k = 8*(lane>>4)+j
__global__ void prep_w(const float* __restrict__ Wg, _Float16* __restrict__ ws) {
  const int t    = blockIdx.x * 256 + threadIdx.x;  // 0..16383 = grp*64 + lane
  const int lane = t & 63;
  const int grp  = t >> 6;                          // ks*4 + nt
  const int e    = (grp & 3) * 16 + (lane & 15);
  const int k0   = (grp >> 2) * 32 + (lane >> 4) * 8;
  const float* src = &Wg[(size_t)e * HIDDEN + k0];
  f16x8 h, l;
#pragma unroll
  for (int j = 0; j < 8; ++j) {
    const float v = src[j];
    const _Float16 hh = (_Float16)v;        // RNE
    h[j] = hh;
    l[j] = (_Float16)(v - (float)hh);       // exact residual, RNE to f16
  }
  *(f16x8*)&ws[(size_t)grp * 1024 + 0   + lane * 8] = h;
  *(f16x8*)&ws[(size_t)grp * 1024 + 512 + lane * 8] = l;
}

// ---- main: split-f16 MFMA router; ws via block-shared LDS (lgkmcnt),
// ---- x via depth-4 register pipeline (vmcnt), counted-vmcnt barriers (T4).
// ---- 256-thread blocks, 2 blocks/CU: desynced chunk barriers across blocks.
__global__ __launch_bounds__(256, 2)   // 256-VGPR cap: no spill
void router_mfma(const float* __restrict__ x, const _Float16* __restrict__ ws,
                 const float* __restrict__ gb, float* __restrict__ out, int T)
{
  __shared__ _Float16 wt[2][CH_HALVES];   // 2 x 32 KB double-buffered ws chunk

  const int tid  = threadIdx.x;
  const int lane = tid & 63;
  const int tok0 = ((int)blockIdx.x * 4 + (tid >> 6)) * 16;   // 64 tok/block
  // A-frag: row(token) = lane&15, k = 8*(lane>>4)+j
  const float* xp = &x[(size_t)(tok0 + (lane & 15)) * HIDDEN + (lane >> 4) * 8];

  f32x4 acch[NT], accl[NT];
#pragma unroll
  for (int nt = 0; nt < NT; ++nt)
#pragma unroll
    for (int j = 0; j < 4; ++j) { acch[nt][j] = 0.f; accl[nt][j] = 0.f; }

  // stage one 4-kstep ws chunk into LDS (8 x gll16 per thread, lane-linear dest)
  auto stage = [&](int buf, int c) {
#pragma unroll
    for (int j = 0; j < 8; ++j) {
      const int s = j * 256 + tid;        // 0..2047 slots of 8 halves
      __builtin_amdgcn_global_load_lds(
          (gbl_u32*)(ws + (size_t)c * CH_HALVES + s * 8),
          (lds_u32*)(&wt[buf][s * 8]), 16, 0, 0);
    }
  };

  // ---- x prefetch pipeline, depth 4 (statically indexed via unroll) ----
  float4 pfa[4], pfb[4];
#pragma unroll
  for (int j = 0; j < 4; ++j) {
    pfa[j] = *(const float4*)(xp + j * 32);
    pfb[j] = *(const float4*)(xp + j * 32 + 4);
  }

  stage(0, 0);
  asm volatile("s_waitcnt vmcnt(0)" ::: "memory");   // prologue: full drain once
  __builtin_amdgcn_s_barrier();

  int cur = 0;
  for (int c = 0; c < NCH; ++c) {
    // issue next chunk's staging FIRST; pin issue order so the counted
    // vmcnt below drains exactly these 8 gll (x refills are newer in FIFO)
    if (c + 1 < NCH) stage(cur ^ 1, c + 1);
    __builtin_amdgcn_sched_barrier(0);

    const _Float16* wbase = &wt[cur][lane * 8];
#pragma unroll
    for (int j = 0; j < 4; ++j) {
      const int ks = c * CHUNK + j;

      // consume x slot j, refill it for ks+4 (stays in flight across barrier)
      const float4 xa = pfa[j], xb = pfb[j];
      if (ks + 4 < KSTEPS) {
        pfa[j] = *(const float4*)(xp + (ks + 4) * 32);
        pfb[j] = *(const float4*)(xp + (ks + 4) * 32 + 4);
      }

      // b-frags from LDS (lgkmcnt pipe; compiler schedules fine-grained waits)
      f16x8 bh[NT], bl[NT];
#pragma unroll
      for (int nt = 0; nt < NT; ++nt) {
        bh[nt] = *(const f16x8*)(wbase + j * 4096 + nt * 1024);
        bl[nt] = *(const f16x8*)(wbase + j * 4096 + nt * 1024 + 512);
      }

      // split x into hi/lo f16 (RNE, residual <= 2^-22) — proven R5 math
      const float xs[8] = {xa.x, xa.y, xa.z, xa.w, xb.x, xb.y, xb.z, xb.w};
      f16x8 ah, al;
#pragma unroll
      for (int q = 0; q < 8; ++q) {
        const _Float16 h = (_Float16)xs[q];
        ah[q] = h;
        al[q] = (_Float16)(xs[q] - (float)h);
      }

#pragma unroll
      for (int nt = 0; nt < NT; ++nt) {
        acch[nt] = __builtin_amdgcn_mfma_f32_16x16x32_f16(ah, bh[nt], acch[nt], 0, 0, 0);
        accl[nt] = __builtin_amdgcn_mfma_f32_16x16x32_f16(ah, bl[nt], accl[nt], 0, 0, 0);
        accl[nt] = __builtin_amdgcn_mfma_f32_16x16x32_f16(al, bh[nt], accl[nt], 0, 0, 0);
      }
    }

    // T4 counted boundary: keep the 8 newest (this chunk's x refills) in
    // flight; drain the 8 staging gll; order LDS reads; raw barrier.
    asm volatile("s_waitcnt vmcnt(8) lgkmcnt(0)" ::: "memory");
    __builtin_amdgcn_s_barrier();
    cur ^= 1;
  }

  // ---- epilogue: C/D row(token)=(lane>>4)*4+reg, col(expert)=lane&15 [m89] ----
  float bias[NT];
#pragma unroll
  for (int nt = 0; nt < NT; ++nt) bias[nt] = gb[nt * 16 + (lane & 15)];

  const int q = lane >> 4;
#pragma unroll
  for (int r = 0; r < 4; ++r) {
    float v1 = acch[0][r] + accl[0][r] + bias[0];
    int   i1 = lane & 15;
    float v2 = -3.402823466e+38f;
    int   i2 = i1;
#pragma unroll
    for (int nt = 1; nt < NT; ++nt) {
      const float v = acch[nt][r] + accl[nt][r] + bias[nt];
      const int  ie = nt * 16 + (lane & 15);
      if (v > v1)      { v2 = v1; i2 = i1; v1 = v; i1 = ie; }
      else if (v > v2) { v2 = v;  i2 = ie; }
    }
#pragma unroll
    for (int m = 1; m <= 8; m <<= 1) {
      const float o1 = __shfl_xor(v1, m, 64); const int oi1 = __shfl_xor(i1, m, 64);
      const float o2 = __shfl_xor(v2, m, 64); const int oi2 = __shfl_xor(i2, m, 64);
      const bool b = (o1 > v1) || (o1 == v1 && oi1 < i1);
      if (b) {
        const bool cnd = (v1 > o2) || (v1 == o2 && i1 < oi2);
        v2 = cnd ? v1 : o2; i2 = cnd ? i1 : oi2;
        v1 = o1; i1 = oi1;
      } else {
        const bool cnd = (o1 > v2) || (o1 == v2 && oi1 < i2);
        if (cnd) { v2 = o1; i2 = oi1; }
      }
    }
    if ((lane & 15) == 0) {
      const int tok = tok0 + q * 4 + r;
      const float e2 = expf(v2 - v1);
      const float s  = 1.f / (1.f + e2);
      out[2 * tok]     = s;                 // weights, descending like top_k
      out[2 * tok + 1] = e2 * s;
      out[2 * T + 2 * tok]     = (float)i1; // idx section (float-encoded)
      out[2 * T + 2 * tok + 1] = (float)i2;
    }
  }
}

// ---------------- fallback (proven R2 kernel) if ws too small ----------------
#define BK 64
#define NK4 (BK/4)
#define NCHUNK (HIDDEN/BK)
#define TPB 512
#define NWAVE 8
#define TPW 8
#define TPBK 64

__global__ __launch_bounds__(TPB, 4)
void router_fb(const float* __restrict__ x, const float* __restrict__ Wg,
               const float* __restrict__ gb, float* __restrict__ out, int T)
{
  __shared__ float4 wlds[2][NK4][NEXP];
  __shared__ float4 xlds[2][NWAVE][TPW][NK4];
  const int tid = threadIdx.x, lane = tid & 63, wid = tid >> 6;
  const int tok0 = (int)blockIdx.x * TPBK + wid * TPW;
  float acc[TPW]; double dacc[TPW];
#pragma unroll
  for (int t = 0; t < TPW; ++t) { acc[t] = 0.f; dacc[t] = 0.0; }
  auto stageW = [&](int buf, int k0) {
#pragma unroll
    for (int j = 0; j < 2; ++j) {
      const int s = tid + j * TPB, e = s & 63, k4 = s >> 6;
      __builtin_amdgcn_global_load_lds((gbl_u32*)&Wg[(size_t)e * HIDDEN + k0 + 4 * k4],
                                       (lds_u32*)&wlds[buf][k4][e], 16, 0, 0);
    }
  };
  auto stageX = [&](int buf, int k0) {
#pragma unroll
    for (int j = 0; j < 2; ++j) {
      const int s = lane + j * 64, t = s >> 4, k4 = s & 15;
      __builtin_amdgcn_global_load_lds((gbl_u32*)&x[(size_t)(tok0 + t) * HIDDEN + k0 + 4 * k4],
                                       (lds_u32*)&xlds[buf][wid][t][k4], 16, 0, 0);
    }
  };
  stageW(0, 0); stageX(0, 0); __syncthreads();
  int cur = 0;
  for (int c = 0; c < NCHUNK; ++c) {
    if (c + 1 < NCHUNK) { stageW(cur ^ 1, (c + 1) * BK); stageX(cur ^ 1, (c + 1) * BK); }
#pragma unroll
    for (int k4 = 0; k4 < NK4; ++k4) {
      const float4 w = wlds[cur][k4][lane];
#pragma unroll
      for (int t = 0; t < TPW; ++t) {
        const float4 xv = xlds[cur][wid][t][k4];
        acc[t] = fmaf(xv.x, w.x, acc[t]); acc[t] = fmaf(xv.y, w.y, acc[t]);
        acc[t] = fmaf(xv.z, w.z, acc[t]); acc[t] = fmaf(xv.w, w.w, acc[t]);
      }
    }
#pragma unroll
    for (int t = 0; t < TPW; ++t) { dacc[t] += (double)acc[t]; acc[t] = 0.f; }
    __syncthreads(); cur ^= 1;
  }
  const float bv = gb[lane];
#pragma unroll
  for (int t = 0; t < TPW; ++t) {
    const float v = (float)dacc[t] + bv;
    float v1 = v; int i1 = lane;
#pragma unroll
    for (int off = 32; off >= 1; off >>= 1) {
      const float ov = __shfl_xor(v1, off, 64); const int oi = __shfl_xor(i1, off, 64);
      if (ov > v1 || (ov == v1 && oi < i1)) { v1 = ov; i1 = oi; }
    }
    float v2 = (lane == i1) ? -3.402823466e+38f : v; int i2 = lane;
#pragma unroll
    for (int off = 32; off >= 1; off >>= 1) {
      const float ov = __shfl_xor(v2, off, 64); const int oi = __shfl_xor(i2, off, 64);
      if (ov > v2 || (ov == v2 && oi < i2)) { v2 = ov; i2 = oi; }
    }
    if (lane == 0) {
      const int tok = tok0 + t;
      const float e2 = expf(v2 - v1), s = 1.f + e2;
      out[2 * tok] = 1.f / s; out[2 * tok + 1] = e2 / s;
      out[2 * T + 2 * tok] = (float)i1; out[2 * T + 2 * tok + 1] = (float)i2;
    }
  }
}

extern "C" void kernel_launch(void* const* d_in, const int* in_sizes, int n_in,
                              void* d_out, int out_size, void* d_ws, size_t ws_size,
                              hipStream_t stream) {
  const float* x  = (const float*)d_in[0];   // [4,8192,2048] f32
  const float* Wg = (const float*)d_in[1];   // [64,2048] f32
  const float* gb = (const float*)d_in[2];   // [64] f32
  float* out = (float*)d_out;
  const int T = in_sizes[0] / HIDDEN;        // 32768 tokens

  if (ws_size >= WS_HALVES * sizeof(_Float16)) {
    _Float16* ws = (_Float16*)d_ws;
    prep_w<<<dim3(64), dim3(256), 0, stream>>>(Wg, ws);
    router_mfma<<<dim3(T / 64), dim3(256), 0, stream>>>(x, ws, gb, out, T);
  } else {
    router_fb<<<dim3(T / TPBK), dim3(TPB), 0, stream>>>(x, Wg, gb, out, T);
  }
}

// Round 9
// 60.764 us; speedup vs baseline: 1.0177x; 1.0177x over previous
//
#include <hip/hip_runtime.h>
#include <math.h>

#define HIDDEN 2048
#define NEXP   64
#define KSTEPS (HIDDEN/32)    // 64 MFMA k-steps
#define NT     4              // four 16-expert N-tiles
#define CHUNK  8              // k-steps per LDS ws chunk (8 boundaries total)
#define NCH    (KSTEPS/CHUNK) // 8
#define CH_HALVES (CHUNK*4096)  // 32768 halves = 64 KB per chunk
#define WS_HALVES (KSTEPS*NT*2*64*8)   // 262144 halves = 512 KB
#define PFD    8              // x prefetch depth (k-steps)

typedef _Float16 f16x8 __attribute__((ext_vector_type(8)));
typedef float    f32x4 __attribute__((ext_vector_type(4)));
typedef __attribute__((address_space(3))) unsigned int       lds_u32;
typedef __attribute__((address_space(1))) const unsigned int gbl_u32;

// ---------------- prep: W -> split-f16 MFMA B-fragments in ws ----------------
// ws halves layout: ks*4096 + nt*1024 + split*512 + lane*8
// B-frag mapping (16x16x32): col(expert) = lane&15, k = 8*(lane>>4)+j
__global__ void prep_w(const float* __restrict__ Wg, _Float16* __restrict__ ws) {
  const int t    = blockIdx.x * 256 + threadIdx.x;  // 0..16383 = grp*64 + lane
  const int lane = t & 63;
  const int grp  = t >> 6;                          // ks*4 + nt
  const int e    = (grp & 3) * 16 + (lane & 15);
  const int k0   = (grp >> 2) * 32 + (lane >> 4) * 8;
  const float* src = &Wg[(size_t)e * HIDDEN + k0];
  f16x8 h, l;
#pragma unroll
  for (int j = 0; j < 8; ++j) {
    const float v = src[j];
    const _Float16 hh = (_Float16)v;        // RNE
    h[j] = hh;
    l[j] = (_Float16)(v - (float)hh);       // exact residual, RNE to f16
  }
  *(f16x8*)&ws[(size_t)grp * 1024 + 0   + lane * 8] = h;
  *(f16x8*)&ws[(size_t)grp * 1024 + 512 + lane * 8] = l;
}

// ---- main: split-f16 MFMA router (R7 structure). ws via block-shared LDS
// ---- (lgkmcnt), x via depth-8 register pipeline (vmcnt), counted-vmcnt
// ---- boundaries (T4), 8 chunks of 8 k-steps, 512 thr / 128 tok per block.
__global__ __launch_bounds__(512, 2)   // 256-VGPR cap: no spill
void router_mfma(const float* __restrict__ x, const _Float16* __restrict__ ws,
                 const float* __restrict__ gb, float* __restrict__ out, int T)
{
  __shared__ _Float16 wt[2][CH_HALVES];   // 2 x 64 KB double-buffered ws chunk

  const int tid  = threadIdx.x;
  const int lane = tid & 63;
  const int tok0 = ((int)blockIdx.x * 8 + (tid >> 6)) * 16;   // 128 tok/block
  // A-frag: row(token) = lane&15, k = 8*(lane>>4)+j
  const float* xp = &x[(size_t)(tok0 + (lane & 15)) * HIDDEN + (lane >> 4) * 8];

  f32x4 acch[NT], accl[NT];
#pragma unroll
  for (int nt = 0; nt < NT; ++nt)
#pragma unroll
    for (int j = 0; j < 4; ++j) { acch[nt][j] = 0.f; accl[nt][j] = 0.f; }

  // stage one 8-kstep ws chunk into LDS (8 x gll16 per thread, lane-linear dest)
  auto stage = [&](int buf, int c) {
#pragma unroll
    for (int j = 0; j < 8; ++j) {
      const int s = j * 512 + tid;        // 0..4095 slots of 8 halves
      __builtin_amdgcn_global_load_lds(
          (gbl_u32*)(ws + (size_t)c * CH_HALVES + s * 8),
          (lds_u32*)(&wt[buf][s * 8]), 16, 0, 0);
    }
  };

  // ---- x prefetch pipeline, depth 8 (statically indexed via unroll) ----
  float4 pfa[PFD], pfb[PFD];
#pragma unroll
  for (int j = 0; j < PFD; ++j) {
    pfa[j] = *(const float4*)(xp + j * 32);
    pfb[j] = *(const float4*)(xp + j * 32 + 4);
  }

  stage(0, 0);
  asm volatile("s_waitcnt vmcnt(0)" ::: "memory");   // prologue: full drain once
  __builtin_amdgcn_s_barrier();

  int cur = 0;
  for (int c = 0; c < NCH; ++c) {
    // issue next chunk's staging FIRST; pin issue order. FIFO at the boundary:
    // [prev chunk's 16 x refills][these 8 staging][this chunk's 16 x refills]
    if (c + 1 < NCH) stage(cur ^ 1, c + 1);
    __builtin_amdgcn_sched_barrier(0);

    const _Float16* wbase = &wt[cur][lane * 8];
#pragma unroll
    for (int j = 0; j < CHUNK; ++j) {
      const int ks = c * CHUNK + j;

      // consume x slot j, refill it for ks+8 (stays in flight across barrier)
      const float4 xa = pfa[j], xb = pfb[j];
      if (ks + PFD < KSTEPS) {
        pfa[j] = *(const float4*)(xp + (ks + PFD) * 32);
        pfb[j] = *(const float4*)(xp + (ks + PFD) * 32 + 4);
      }

      // b-frags from LDS (lgkmcnt pipe; compiler schedules fine-grained waits)
      f16x8 bh[NT], bl[NT];
#pragma unroll
      for (int nt = 0; nt < NT; ++nt) {
        bh[nt] = *(const f16x8*)(wbase + j * 4096 + nt * 1024);
        bl[nt] = *(const f16x8*)(wbase + j * 4096 + nt * 1024 + 512);
      }

      // split x into hi/lo f16 (RNE, residual <= 2^-22) — proven R5 math
      const float xs[8] = {xa.x, xa.y, xa.z, xa.w, xb.x, xb.y, xb.z, xb.w};
      f16x8 ah, al;
#pragma unroll
      for (int q = 0; q < 8; ++q) {
        const _Float16 h = (_Float16)xs[q];
        ah[q] = h;
        al[q] = (_Float16)(xs[q] - (float)h);
      }

#pragma unroll
      for (int nt = 0; nt < NT; ++nt) {
        acch[nt] = __builtin_amdgcn_mfma_f32_16x16x32_f16(ah, bh[nt], acch[nt], 0, 0, 0);
        accl[nt] = __builtin_amdgcn_mfma_f32_16x16x32_f16(ah, bl[nt], accl[nt], 0, 0, 0);
        accl[nt] = __builtin_amdgcn_mfma_f32_16x16x32_f16(al, bh[nt], accl[nt], 0, 0, 0);
      }
    }

    // T4 counted boundary: keep this chunk's 16 x refills in flight; drain
    // prev refills (long done) + the 8 staging gll; order LDS reads; barrier.
    asm volatile("s_waitcnt vmcnt(16) lgkmcnt(0)" ::: "memory");
    __builtin_amdgcn_s_barrier();
    cur ^= 1;
  }

  // ---- epilogue: C/D row(token)=(lane>>4)*4+reg, col(expert)=lane&15 [m89] ----
  float bias[NT];
#pragma unroll
  for (int nt = 0; nt < NT; ++nt) bias[nt] = gb[nt * 16 + (lane & 15)];

  const int q = lane >> 4;
#pragma unroll
  for (int r = 0; r < 4; ++r) {
    float v1 = acch[0][r] + accl[0][r] + bias[0];
    int   i1 = lane & 15;
    float v2 = -3.402823466e+38f;
    int   i2 = i1;
#pragma unroll
    for (int nt = 1; nt < NT; ++nt) {
      const float v = acch[nt][r] + accl[nt][r] + bias[nt];
      const int  ie = nt * 16 + (lane & 15);
      if (v > v1)      { v2 = v1; i2 = i1; v1 = v; i1 = ie; }
      else if (v > v2) { v2 = v;  i2 = ie; }
    }
#pragma unroll
    for (int m = 1; m <= 8; m <<= 1) {
      const float o1 = __shfl_xor(v1, m, 64); const int oi1 = __shfl_xor(i1, m, 64);
      const float o2 = __shfl_xor(v2, m, 64); const int oi2 = __shfl_xor(i2, m, 64);
      const bool b = (o1 > v1) || (o1 == v1 && oi1 < i1);
      if (b) {
        const bool cnd = (v1 > o2) || (v1 == o2 && i1 < oi2);
        v2 = cnd ? v1 : o2; i2 = cnd ? i1 : oi2;
        v1 = o1; i1 = oi1;
      } else {
        const bool cnd = (o1 > v2) || (o1 == v2 && oi1 < i2);
        if (cnd) { v2 = o1; i2 = oi1; }
      }
    }
    if ((lane & 15) == 0) {
      const int tok = tok0 + q * 4 + r;
      const float e2 = expf(v2 - v1);
      const float s  = 1.f / (1.f + e2);
      out[2 * tok]     = s;                 // weights, descending like top_k
      out[2 * tok + 1] = e2 * s;
      out[2 * T + 2 * tok]     = (float)i1; // idx section (float-encoded)
      out[2 * T + 2 * tok + 1] = (float)i2;
    }
  }
}

// ---------------- fallback (proven R2 kernel) if ws too small ----------------
#define BK 64
#define NK4 (BK/4)
#define NCHUNK (HIDDEN/BK)
#define TPB 512
#define NWAVE 8
#define TPW 8
#define TPBK 64

__global__ __launch_bounds__(TPB, 4)
void router_fb(const float* __restrict__ x, const float* __restrict__ Wg,
               const float* __restrict__ gb, float* __restrict__ out, int T)
{
  __shared__ float4 wlds[2][NK4][NEXP];
  __shared__ float4 xlds[2][NWAVE][TPW][NK4];
  const int tid = threadIdx.x, lane = tid & 63, wid = tid >> 6;
  const int tok0 = (int)blockIdx.x * TPBK + wid * TPW;
  float acc[TPW]; double dacc[TPW];
#pragma unroll
  for (int t = 0; t < TPW; ++t) { acc[t] = 0.f; dacc[t] = 0.0; }
  auto stageW = [&](int buf, int k0) {
#pragma unroll
    for (int j = 0; j < 2; ++j) {
      const int s = tid + j * TPB, e = s & 63, k4 = s >> 6;
      __builtin_amdgcn_global_load_lds((gbl_u32*)&Wg[(size_t)e * HIDDEN + k0 + 4 * k4],
                                       (lds_u32*)&wlds[buf][k4][e], 16, 0, 0);
    }
  };
  auto stageX = [&](int buf, int k0) {
#pragma unroll
    for (int j = 0; j < 2; ++j) {
      const int s = lane + j * 64, t = s >> 4, k4 = s & 15;
      __builtin_amdgcn_global_load_lds((gbl_u32*)&x[(size_t)(tok0 + t) * HIDDEN + k0 + 4 * k4],
                                       (lds_u32*)&xlds[buf][wid][t][k4], 16, 0, 0);
    }
  };
  stageW(0, 0); stageX(0, 0); __syncthreads();
  int cur = 0;
  for (int c = 0; c < NCHUNK; ++c) {
    if (c + 1 < NCHUNK) { stageW(cur ^ 1, (c + 1) * BK); stageX(cur ^ 1, (c + 1) * BK); }
#pragma unroll
    for (int k4 = 0; k4 < NK4; ++k4) {
      const float4 w = wlds[cur][k4][lane];
#pragma unroll
      for (int t = 0; t < TPW; ++t) {
        const float4 xv = xlds[cur][wid][t][k4];
        acc[t] = fmaf(xv.x, w.x, acc[t]); acc[t] = fmaf(xv.y, w.y, acc[t]);
        acc[t] = fmaf(xv.z, w.z, acc[t]); acc[t] = fmaf(xv.w, w.w, acc[t]);
      }
    }
#pragma unroll
    for (int t = 0; t < TPW; ++t) { dacc[t] += (double)acc[t]; acc[t] = 0.f; }
    __syncthreads(); cur ^= 1;
  }
  const float bv = gb[lane];
#pragma unroll
  for (int t = 0; t < TPW; ++t) {
    const float v = (float)dacc[t] + bv;
    float v1 = v; int i1 = lane;
#pragma unroll
    for (int off = 32; off >= 1; off >>= 1) {
      const float ov = __shfl_xor(v1, off, 64); const int oi = __shfl_xor(i1, off, 64);
      if (ov > v1 || (ov == v1 && oi < i1)) { v1 = ov; i1 = oi; }
    }
    float v2 = (lane == i1) ? -3.402823466e+38f : v; int i2 = lane;
#pragma unroll
    for (int off = 32; off >= 1; off >>= 1) {
      const float ov = __shfl_xor(v2, off, 64); const int oi = __shfl_xor(i2, off, 64);
      if (ov > v2 || (ov == v2 && oi < i2)) { v2 = ov; i2 = oi; }
    }
    if (lane == 0) {
      const int tok = tok0 + t;
      const float e2 = expf(v2 - v1), s = 1.f + e2;
      out[2 * tok] = 1.f / s; out[2 * tok + 1] = e2 / s;
      out[2 * T + 2 * tok] = (float)i1; out[2 * T + 2 * tok + 1] = (float)i2;
    }
  }
}

extern "C" void kernel_launch(void* const* d_in, const int* in_sizes, int n_in,
                              void* d_out, int out_size, void* d_ws, size_t ws_size,
                              hipStream_t stream) {
  const float* x  = (const float*)d_in[0];   // [4,8192,2048] f32
  const float* Wg = (const float*)d_in[1];   // [64,2048] f32
  const float* gb = (const float*)d_in[2];   // [64] f32
  float* out = (float*)d_out;
  const int T = in_sizes[0] / HIDDEN;        // 32768 tokens

  if (ws_size >= WS_HALVES * sizeof(_Float16)) {
    _Float16* ws = (_Float16*)d_ws;
    prep_w<<<dim3(64), dim3(256), 0, stream>>>(Wg, ws);
    router_mfma<<<dim3(T / 128), dim3(512), 0, stream>>>(x, ws, gb, out, T);
  } else {
    router_fb<<<dim3(T / TPBK), dim3(TPB), 0, stream>>>(x, Wg, gb, out, T);
  }
}

// Round 10
// 58.072 us; speedup vs baseline: 1.0649x; 1.0464x over previous
//
#include <hip/hip_runtime.h>
#include <math.h>

#define HIDDEN 2048
#define NEXP   64
#define KSTEPS (HIDDEN/32)    // 64 MFMA k-steps
#define NT     4              // four 16-expert N-tiles
#define CHUNK  4              // k-steps per LDS ws chunk
#define NCH    (KSTEPS/CHUNK) // 16
#define CH_HALVES (CHUNK*4096)  // 16384 halves = 32 KB per chunk
#define WS_HALVES (KSTEPS*NT*2*64*8)   // 262144 halves = 512 KB

typedef _Float16 f16x8 __attribute__((ext_vector_type(8)));
typedef float    f32x4 __attribute__((ext_vector_type(4)));
typedef __attribute__((address_space(3))) unsigned int       lds_u32;
typedef __attribute__((address_space(1))) const unsigned int gbl_u32;

// ---------------- prep: W -> split-f16 MFMA B-fragments in ws ----------------
// ws halves layout: ks*4096 + nt*1024 + split*512 + lane*8
// B-frag mapping (16x16x32): col(expert) = lane&15, k = 8*(lane>>4)+j
__global__ void prep_w(const float* __restrict__ Wg, _Float16* __restrict__ ws) {
  const int t    = blockIdx.x * 256 + threadIdx.x;  // 0..16383 = grp*64 + lane
  const int lane = t & 63;
  const int grp  = t >> 6;                          // ks*4 + nt
  const int e    = (grp & 3) * 16 + (lane & 15);
  const int k0   = (grp >> 2) * 32 + (lane >> 4) * 8;
  const float* src = &Wg[(size_t)e * HIDDEN + k0];
  f16x8 h, l;
#pragma unroll
  for (int j = 0; j < 8; ++j) {
    const float v = src[j];
    const _Float16 hh = (_Float16)v;        // RNE
    h[j] = hh;
    l[j] = (_Float16)(v - (float)hh);       // exact residual, RNE to f16
  }
  *(f16x8*)&ws[(size_t)grp * 1024 + 0   + lane * 8] = h;
  *(f16x8*)&ws[(size_t)grp * 1024 + 512 + lane * 8] = l;
}

// ---- main: split-f16 MFMA router; ws via block-shared LDS (lgkmcnt),
// ---- x via depth-4 register pipeline (vmcnt), counted-vmcnt barriers (T4).
// ---- R7 configuration: 512 thr / 128 tok per block, 16 chunks of 4 k-steps.
// ---- Measured 58.0 us; R8 (2 blocks/CU) and R9 (CHUNK=8/PFD=8) both regressed.
__global__ __launch_bounds__(512, 2)   // 256-VGPR cap: no spill
void router_mfma(const float* __restrict__ x, const _Float16* __restrict__ ws,
                 const float* __restrict__ gb, float* __restrict__ out, int T)
{
  __shared__ _Float16 wt[2][CH_HALVES];   // 2 x 32 KB double-buffered ws chunk

  const int tid  = threadIdx.x;
  const int lane = tid & 63;
  const int tok0 = ((int)blockIdx.x * 8 + (tid >> 6)) * 16;   // 128 tok/block
  // A-frag: row(token) = lane&15, k = 8*(lane>>4)+j
  const float* xp = &x[(size_t)(tok0 + (lane & 15)) * HIDDEN + (lane >> 4) * 8];

  f32x4 acch[NT], accl[NT];
#pragma unroll
  for (int nt = 0; nt < NT; ++nt)
#pragma unroll
    for (int j = 0; j < 4; ++j) { acch[nt][j] = 0.f; accl[nt][j] = 0.f; }

  // stage one 4-kstep ws chunk into LDS (4 x gll16 per thread, lane-linear dest)
  auto stage = [&](int buf, int c) {
#pragma unroll
    for (int j = 0; j < 4; ++j) {
      const int s = j * 512 + tid;        // 0..2047 slots of 8 halves
      __builtin_amdgcn_global_load_lds(
          (gbl_u32*)(ws + (size_t)c * CH_HALVES + s * 8),
          (lds_u32*)(&wt[buf][s * 8]), 16, 0, 0);
    }
  };

  // ---- x prefetch pipeline, depth 4 (statically indexed via unroll) ----
  float4 pfa[4], pfb[4];
#pragma unroll
  for (int j = 0; j < 4; ++j) {
    pfa[j] = *(const float4*)(xp + j * 32);
    pfb[j] = *(const float4*)(xp + j * 32 + 4);
  }

  stage(0, 0);
  asm volatile("s_waitcnt vmcnt(0)" ::: "memory");   // prologue: full drain once
  __builtin_amdgcn_s_barrier();

  int cur = 0;
  for (int c = 0; c < NCH; ++c) {
    // issue next chunk's staging FIRST; pin issue order so the counted
    // vmcnt below drains exactly these 4 gll (and no x refill precedes them)
    if (c + 1 < NCH) stage(cur ^ 1, c + 1);
    __builtin_amdgcn_sched_barrier(0);

    const _Float16* wbase = &wt[cur][lane * 8];
#pragma unroll
    for (int j = 0; j < 4; ++j) {
      const int ks = c * CHUNK + j;

      // consume x slot j, refill it for ks+4 (stays in flight across barrier)
      const float4 xa = pfa[j], xb = pfb[j];
      if (ks + 4 < KSTEPS) {
        pfa[j] = *(const float4*)(xp + (ks + 4) * 32);
        pfb[j] = *(const float4*)(xp + (ks + 4) * 32 + 4);
      }

      // b-frags from LDS (lgkmcnt pipe; compiler schedules fine-grained waits)
      f16x8 bh[NT], bl[NT];
#pragma unroll
      for (int nt = 0; nt < NT; ++nt) {
        bh[nt] = *(const f16x8*)(wbase + j * 4096 + nt * 1024);
        bl[nt] = *(const f16x8*)(wbase + j * 4096 + nt * 1024 + 512);
      }

      // split x into hi/lo f16 (RNE, residual <= 2^-22) — proven R5 math
      const float xs[8] = {xa.x, xa.y, xa.z, xa.w, xb.x, xb.y, xb.z, xb.w};
      f16x8 ah, al;
#pragma unroll
      for (int q = 0; q < 8; ++q) {
        const _Float16 h = (_Float16)xs[q];
        ah[q] = h;
        al[q] = (_Float16)(xs[q] - (float)h);
      }

#pragma unroll
      for (int nt = 0; nt < NT; ++nt) {
        acch[nt] = __builtin_amdgcn_mfma_f32_16x16x32_f16(ah, bh[nt], acch[nt], 0, 0, 0);
        accl[nt] = __builtin_amdgcn_mfma_f32_16x16x32_f16(ah, bl[nt], accl[nt], 0, 0, 0);
        accl[nt] = __builtin_amdgcn_mfma_f32_16x16x32_f16(al, bh[nt], accl[nt], 0, 0, 0);
      }
    }

    // T4 counted boundary: keep the 8 newest (this chunk's x refills) in
    // flight; drain the 4 staging gll; order LDS reads; raw barrier.
    asm volatile("s_waitcnt vmcnt(8) lgkmcnt(0)" ::: "memory");
    __builtin_amdgcn_s_barrier();
    cur ^= 1;
  }

  // ---- epilogue: C/D row(token)=(lane>>4)*4+reg, col(expert)=lane&15 [m89] ----
  float bias[NT];
#pragma unroll
  for (int nt = 0; nt < NT; ++nt) bias[nt] = gb[nt * 16 + (lane & 15)];

  const int q = lane >> 4;
#pragma unroll
  for (int r = 0; r < 4; ++r) {
    float v1 = acch[0][r] + accl[0][r] + bias[0];
    int   i1 = lane & 15;
    float v2 = -3.402823466e+38f;
    int   i2 = i1;
#pragma unroll
    for (int nt = 1; nt < NT; ++nt) {
      const float v = acch[nt][r] + accl[nt][r] + bias[nt];
      const int  ie = nt * 16 + (lane & 15);
      if (v > v1)      { v2 = v1; i2 = i1; v1 = v; i1 = ie; }
      else if (v > v2) { v2 = v;  i2 = ie; }
    }
#pragma unroll
    for (int m = 1; m <= 8; m <<= 1) {
      const float o1 = __shfl_xor(v1, m, 64); const int oi1 = __shfl_xor(i1, m, 64);
      const float o2 = __shfl_xor(v2, m, 64); const int oi2 = __shfl_xor(i2, m, 64);
      const bool b = (o1 > v1) || (o1 == v1 && oi1 < i1);
      if (b) {
        const bool cnd = (v1 > o2) || (v1 == o2 && i1 < oi2);
        v2 = cnd ? v1 : o2; i2 = cnd ? i1 : oi2;
        v1 = o1; i1 = oi1;
      } else {
        const bool cnd = (o1 > v2) || (o1 == v2 && oi1 < i2);
        if (cnd) { v2 = o1; i2 = oi1; }
      }
    }
    if ((lane & 15) == 0) {
      const int tok = tok0 + q * 4 + r;
      const float e2 = expf(v2 - v1);
      const float s  = 1.f / (1.f + e2);
      out[2 * tok]     = s;                 // weights, descending like top_k
      out[2 * tok + 1] = e2 * s;
      out[2 * T + 2 * tok]     = (float)i1; // idx section (float-encoded)
      out[2 * T + 2 * tok + 1] = (float)i2;
    }
  }
}

// ---------------- fallback (proven R2 kernel) if ws too small ----------------
#define BK 64
#define NK4 (BK/4)
#define NCHUNK (HIDDEN/BK)
#define TPB 512
#define NWAVE 8
#define TPW 8
#define TPBK 64

__global__ __launch_bounds__(TPB, 4)
void router_fb(const float* __restrict__ x, const float* __restrict__ Wg,
               const float* __restrict__ gb, float* __restrict__ out, int T)
{
  __shared__ float4 wlds[2][NK4][NEXP];
  __shared__ float4 xlds[2][NWAVE][TPW][NK4];
  const int tid = threadIdx.x, lane = tid & 63, wid = tid >> 6;
  const int tok0 = (int)blockIdx.x * TPBK + wid * TPW;
  float acc[TPW]; double dacc[TPW];
#pragma unroll
  for (int t = 0; t < TPW; ++t) { acc[t] = 0.f; dacc[t] = 0.0; }
  auto stageW = [&](int buf, int k0) {
#pragma unroll
    for (int j = 0; j < 2; ++j) {
      const int s = tid + j * TPB, e = s & 63, k4 = s >> 6;
      __builtin_amdgcn_global_load_lds((gbl_u32*)&Wg[(size_t)e * HIDDEN + k0 + 4 * k4],
                                       (lds_u32*)&wlds[buf][k4][e], 16, 0, 0);
    }
  };
  auto stageX = [&](int buf, int k0) {
#pragma unroll
    for (int j = 0; j < 2; ++j) {
      const int s = lane + j * 64, t = s >> 4, k4 = s & 15;
      __builtin_amdgcn_global_load_lds((gbl_u32*)&x[(size_t)(tok0 + t) * HIDDEN + k0 + 4 * k4],
                                       (lds_u32*)&xlds[buf][wid][t][k4], 16, 0, 0);
    }
  };
  stageW(0, 0); stageX(0, 0); __syncthreads();
  int cur = 0;
  for (int c = 0; c < NCHUNK; ++c) {
    if (c + 1 < NCHUNK) { stageW(cur ^ 1, (c + 1) * BK); stageX(cur ^ 1, (c + 1) * BK); }
#pragma unroll
    for (int k4 = 0; k4 < NK4; ++k4) {
      const float4 w = wlds[cur][k4][lane];
#pragma unroll
      for (int t = 0; t < TPW; ++t) {
        const float4 xv = xlds[cur][wid][t][k4];
        acc[t] = fmaf(xv.x, w.x, acc[t]); acc[t] = fmaf(xv.y, w.y, acc[t]);
        acc[t] = fmaf(xv.z, w.z, acc[t]); acc[t] = fmaf(xv.w, w.w, acc[t]);
      }
    }
#pragma unroll
    for (int t = 0; t < TPW; ++t) { dacc[t] += (double)acc[t]; acc[t] = 0.f; }
    __syncthreads(); cur ^= 1;
  }
  const float bv = gb[lane];
#pragma unroll
  for (int t = 0; t < TPW; ++t) {
    const float v = (float)dacc[t] + bv;
    float v1 = v; int i1 = lane;
#pragma unroll
    for (int off = 32; off >= 1; off >>= 1) {
      const float ov = __shfl_xor(v1, off, 64); const int oi = __shfl_xor(i1, off, 64);
      if (ov > v1 || (ov == v1 && oi < i1)) { v1 = ov; i1 = oi; }
    }
    float v2 = (lane == i1) ? -3.402823466e+38f : v; int i2 = lane;
#pragma unroll
    for (int off = 32; off >= 1; off >>= 1) {
      const float ov = __shfl_xor(v2, off, 64); const int oi = __shfl_xor(i2, off, 64);
      if (ov > v2 || (ov == v2 && oi < i2)) { v2 = ov; i2 = oi; }
    }
    if (lane == 0) {
      const int tok = tok0 + t;
      const float e2 = expf(v2 - v1), s = 1.f + e2;
      out[2 * tok] = 1.f / s; out[2 * tok + 1] = e2 / s;
      out[2 * T + 2 * tok] = (float)i1; out[2 * T + 2 * tok + 1] = (float)i2;
    }
  }
}

extern "C" void kernel_launch(void* const* d_in, const int* in_sizes, int n_in,
                              void* d_out, int out_size, void* d_ws, size_t ws_size,
                              hipStream_t stream) {
  const float* x  = (const float*)d_in[0];   // [4,8192,2048] f32
  const float* Wg = (const float*)d_in[1];   // [64,2048] f32
  const float* gb = (const float*)d_in[2];   // [64] f32
  float* out = (float*)d_out;
  const int T = in_sizes[0] / HIDDEN;        // 32768 tokens

  if (ws_size >= WS_HALVES * sizeof(_Float16)) {
    _Float16* ws = (_Float16*)d_ws;
    prep_w<<<dim3(64), dim3(256), 0, stream>>>(Wg, ws);
    router_mfma<<<dim3(T / 128), dim3(512), 0, stream>>>(x, ws, gb, out, T);
  } else {
    router_fb<<<dim3(T / TPBK), dim3(TPB), 0, stream>>>(x, Wg, gb, out, T);
  }
}